// Round 14
// baseline (74.522 us; speedup 1.0000x reference)
//
#include <hip/hip_runtime.h>

// MesoLayer R13: R9's reg-staged 2-deep pipeline (best, 47.3us) scaled to
// 4 blocks/CU (16 waves/CU) to overlap per-phase sync glue across blocks.
// Block = 256 threads = 128 rows; 16 phases x 8-row chunks (780 float4).
// Phase p: FLUSH(p-1) -> ISSUE(chunk p+2 -> set[p&1]) -> COMPUTE(buf[p&1])
//          -> WAITC(chunk p+1) -> WRITE(set[(p+1)&1] -> buf[(p+1)&1]) -> BAR.
// Per-wave VMEM/phase: wv0-2 = 3 loads + 1 flush store, wv3 = 4 loads + 0
// -> steady WAITC uniform vmcnt(4). LDS 27.2 KB, __launch_bounds__(256,4).

static __device__ __forceinline__ float xsum(float a) {
  a += __shfl_xor(a, 8, 64);
  a += __shfl_xor(a, 16, 64);
  a += __shfl_xor(a, 32, 64);
  return a;
}
static __device__ __forceinline__ float xmax(float a) {
  a = fmaxf(a, __shfl_xor(a, 8, 64));
  a = fmaxf(a, __shfl_xor(a, 16, 64));
  a = fmaxf(a, __shfl_xor(a, 32, 64));
  return a;
}

// 64-lane segment over 8 rows: lane (q=ln>>3, r=ln&7) covers row r,
// j in {q, q+8, ...}; reduce over q via shfl_xor 8/16/32 (pipe-equivalent to
// DPP per R12); true global max -> single-pass exp. Mt = upper-tri(W W^T).
// Bank check: (6r+5q+..)%32 worst-case 2-way aliasing = free (m136).
template<int L, int SEGOFF, int OUTOFF>
__device__ __forceinline__ void seg64(const float* __restrict__ bp, int q,
                                      const float (&Mt)[15],
                                      float* __restrict__ ob) {
  constexpr int T[5][5] = {{0, 1, 2, 3, 4},  {1, 5, 6, 7, 8},
                           {2, 6, 9, 10, 11}, {3, 7, 10, 12, 13},
                           {4, 8, 11, 13, 14}};
  constexpr int NJ = (L + 7) / 8;
  const bool lastv = (q + 8 * (NJ - 1)) < L;

  float s[NJ][5];
#pragma unroll
  for (int k = 0; k < NJ; ++k) {
    int j = q + 8 * k;
    if (j > L - 1) j = L - 1;  // only last k can clamp
#pragma unroll
    for (int g = 0; g < 5; ++g) s[k][g] = bp[SEGOFF + j * 5 + g];
  }
#pragma unroll
  for (int g = 0; g < 5; ++g) s[NJ - 1][g] = lastv ? s[NJ - 1][g] : 0.f;

  float ssl[5];
#pragma unroll
  for (int g = 0; g < 5; ++g) {
    float a = s[0][g];
#pragma unroll
    for (int k = 1; k < NJ; ++k) a += s[k][g];
    ssl[g] = xsum(a);  // full subsum on all lanes
  }

  float v[5];
#pragma unroll
  for (int g = 0; g < 5; ++g) {
    float a = Mt[T[g][0]] * ssl[0];
#pragma unroll
    for (int h = 1; h < 5; ++h) a += Mt[T[g][h]] * ssl[h];
    v[g] = a;
  }

  float sc[NJ];
#pragma unroll
  for (int k = 0; k < NJ; ++k) {
    float a = s[k][0] * v[0];
#pragma unroll
    for (int g = 1; g < 5; ++g) a += s[k][g] * v[g];
    sc[k] = a;
  }
  sc[NJ - 1] = lastv ? sc[NJ - 1] : -3.0e38f;

  float ml = sc[0];
#pragma unroll
  for (int k = 1; k < NJ; ++k) ml = fmaxf(ml, sc[k]);
  float m = xmax(ml);

  float d = 0.f, pl[5] = {0.f, 0.f, 0.f, 0.f, 0.f};
#pragma unroll
  for (int k = 0; k < NJ; ++k) {
    float e = __expf(sc[k] - m);  // masked k: exp(-huge)=0
    d += e;
#pragma unroll
    for (int g = 0; g < 5; ++g) pl[g] += e * s[k][g];
  }
  d = xsum(d);
  float inv = 1.0f / d;
#pragma unroll
  for (int g = 0; g < 5; ++g) pl[g] = xsum(pl[g]);
  if (q == 0) {
#pragma unroll
    for (int g = 0; g < 5; ++g) ob[OUTOFF + g] = pl[g] * inv;
  }
}

// LDS (floats): buf0 [0,3120) | buf1 [3120,6240) | out0 [6240,6520) |
// out1 [6520,6800). Total 27200 B -> 4+ blocks/CU.
__global__ __launch_bounds__(256, 4) void meso_kernel(
    const float* __restrict__ x, const float* __restrict__ w,
    float* __restrict__ out) {
  __shared__ __align__(16) float smf[6800];
  float4* sm4 = (float4*)smf;
  float2* sm2 = (float2*)smf;
  const int t = threadIdx.x;
  const int wv = t >> 6, ln = t & 63, q = ln >> 3, r = ln & 7;
  const size_t blk = blockIdx.x;
  const float4* xp4 = (const float4*)x + blk * 12480;  // 128*390/4
  float2* o2 = (float2*)out + blk * 2240;              // 128*35/2

  float4 A0, A1, A2, A3 = make_float4(0, 0, 0, 0);
  float4 B0, B1, B2, B3 = make_float4(0, 0, 0, 0);

  // Chunk = 780 fl4: 3 full-wave loads + 12-lane tail on WAVE 3 (t>=244),
  // so flush (waves 0-2) + tail (wave 3) balance VMEM counts -> uniform wait.
#define ISSUE(R, c)                                                    \
  { const float4* g_ = xp4 + (size_t)(c) * 780;                        \
    R##0 = g_[t]; R##1 = g_[t + 256]; R##2 = g_[t + 512];              \
    if (t >= 244) R##3 = g_[524 + t]; }

#define WRITE(R, b)                                                    \
  { float4* l_ = sm4 + (b) * 780;                                      \
    l_[t] = R##0; l_[t + 256] = R##1; l_[t + 512] = R##2;              \
    if (t >= 244) l_[524 + t] = R##3; }

#define WAITC(n03, n3)                                                 \
  { if (wv == 3) asm volatile("s_waitcnt vmcnt(" #n3 ")" ::: "memory");\
    else         asm volatile("s_waitcnt vmcnt(" #n03 ")" ::: "memory"); }

#define BAR()                                                          \
  { asm volatile("s_waitcnt lgkmcnt(0)" ::: "memory");                 \
    __builtin_amdgcn_s_barrier();                                      \
    __builtin_amdgcn_sched_barrier(0); }

  // flush(pp): 8 rows * 35 fl = 140 float2, lanes t<140 -> 1 store on each
  // of waves 0-2, none on wave 3.
#define FLUSH(pp)                                                      \
  { if (t < 140)                                                       \
      o2[(size_t)(pp) * 140 + t] = sm2[3120 + ((pp) & 1) * 140 + t]; }

#define COMPUTE(par)                                                   \
  { const float* bp = smf + (par) * 3120 + r * 390;                    \
    float* ob = smf + 6240 + (par) * 280 + r * 35;                     \
    if (wv == 0) { seg64<25, 115, 15>(bp, q, Mt, ob); }                \
    else if (wv == 1) { seg64<12, 330, 30>(bp, q, Mt, ob);             \
                        seg64<5,  0,   0 >(bp, q, Mt, ob); }           \
    else if (wv == 2) { seg64<9,  25,  5 >(bp, q, Mt, ob);             \
                        seg64<9,  70,  10>(bp, q, Mt, ob); }           \
    else              { seg64<9,  240, 20>(bp, q, Mt, ob);             \
                        seg64<9,  285, 25>(bp, q, Mt, ob); } }

  ISSUE(A, 0)
  ISSUE(B, 1)

  // Mt = upper-tri(W W^T): uniform scalar loads under the load shadow.
  float Mt[15];
  {
    int i = 0;
#pragma unroll
    for (int g = 0; g < 5; ++g)
#pragma unroll
      for (int h = g; h < 5; ++h, ++i) {
        float a = 0.f;
#pragma unroll
        for (int k = 0; k < 10; ++k) a += w[g * 10 + k] * w[h * 10 + k];
        Mt[i] = a;
      }
  }

  WAITC(3, 4)  // chunk0 done (newer = chunk1's 3/4 loads)
  WRITE(A, 0)
  BAR()

  // WAITC audit: p=0: newer = ISSUE(2) only -> (3,4).
  // p=1..13: newer = flush store(wv0-2) + ISSUE 3/4 -> uniform (4,4).
  // p=14: newer = flush(13... at p=14: flush@14) store only -> (1,0).
#pragma unroll 1
  for (int p = 0; p < 16; p += 2) {
    // ---- even phase p: compute buf0/out0; B holds chunk p+1 ----
    if (p > 0) FLUSH(p - 1)
    if (p + 2 < 16) ISSUE(A, p + 2)
    COMPUTE(0)
    if (p == 0)      WAITC(3, 4)
    else if (p < 14) WAITC(4, 4)
    else             WAITC(1, 0)
    WRITE(B, 1)
    BAR()

    // ---- odd phase p+1: compute buf1/out1; A holds chunk p+2 ----
    FLUSH(p)
    if (p + 3 < 16) ISSUE(B, p + 3)
    COMPUTE(1)
    if (p + 2 < 16) {
      if (p + 1 < 14) WAITC(4, 4)
      else            WAITC(1, 0)
      WRITE(A, 0)
    }
    BAR()
  }
  FLUSH(15)
}

extern "C" void kernel_launch(void* const* d_in, const int* in_sizes, int n_in,
                              void* d_out, int out_size, void* d_ws, size_t ws_size,
                              hipStream_t stream) {
  const float* x = (const float*)d_in[0];
  const float* w = (const float*)d_in[1];
  float* out = (float*)d_out;
  int B = in_sizes[0] / 390;  // 131072
  int grid = B / 128;         // 1024 blocks = 4/CU resident
  meso_kernel<<<grid, 256, 0, stream>>>(x, w, out);
}

// Round 15
// 41.000 us; speedup vs baseline: 1.8176x; 1.8176x over previous
//
#include <hip/hip_runtime.h>

// MesoLayer R14: R12's kernel (R9 skeleton, 47.3-47.8us) with the cross-lane
// reduces implemented as TRUE DPP quad_perm (VALU pipe, ~8cy/step) instead of
// __shfl_xor (which lowers to ds_swizzle/bpermute on the LDS pipe, ~60cy,
// chained 8+ deep per segment = the suspected ~0.9us/phase residual).
// R12's "DPP" test never verified the asm -- this one forces it via
// __builtin_amdgcn_mov_dpp (quad_perm xor1=0xB1, xor2=0x4E).
// Block = 256 threads = 256 rows, 16 chunks x 16 rows (1560 float4 flat).
// Phase p: FLUSH(p-1) -> ISSUE(chunk p+2) -> COMPUTE(p) -> WAITC(chunk p+1)
// -> WRITE -> lgkm0+barrier.

static __device__ __forceinline__ float dpp_xor1(float a) {
  return __int_as_float(__builtin_amdgcn_mov_dpp(
      __float_as_int(a), 0xB1, 0xF, 0xF, false));  // quad_perm [1,0,3,2]
}
static __device__ __forceinline__ float dpp_xor2(float a) {
  return __int_as_float(__builtin_amdgcn_mov_dpp(
      __float_as_int(a), 0x4E, 0xF, 0xF, false));  // quad_perm [2,3,0,1]
}
static __device__ __forceinline__ float xsum(float a) {
  a += dpp_xor1(a);
  a += dpp_xor2(a);
  return a;
}
static __device__ __forceinline__ float xmax(float a) {
  a = fmaxf(a, dpp_xor1(a));
  a = fmaxf(a, dpp_xor2(a));
  return a;
}

// 64-lane segment: lane (q=ln&3, r=ln>>2) covers row r, j in {q, q+4, ...};
// reduce over q via DPP quad_perm (lanes of a quad = the 4 j-groups);
// true global max -> single-pass exp. Mt = upper-tri of M = W W^T.
template<int L, int SEGOFF, int OUTOFF>
__device__ __forceinline__ void seg64(const float* __restrict__ bp, int q,
                                      const float (&Mt)[15],
                                      float* __restrict__ ob) {
  constexpr int T[5][5] = {{0, 1, 2, 3, 4},  {1, 5, 6, 7, 8},
                           {2, 6, 9, 10, 11}, {3, 7, 10, 12, 13},
                           {4, 8, 11, 13, 14}};
  constexpr int NJ = (L + 3) / 4;
  const bool lastv = (q + 4 * (NJ - 1)) < L;

  float s[NJ][5];
#pragma unroll
  for (int k = 0; k < NJ; ++k) {
    int j = q + 4 * k;
    if (j > L - 1) j = L - 1;  // only last k can clamp
#pragma unroll
    for (int g = 0; g < 5; ++g) s[k][g] = bp[SEGOFF + j * 5 + g];
  }
#pragma unroll
  for (int g = 0; g < 5; ++g) s[NJ - 1][g] = lastv ? s[NJ - 1][g] : 0.f;

  float ssl[5];
#pragma unroll
  for (int g = 0; g < 5; ++g) {
    float a = s[0][g];
#pragma unroll
    for (int k = 1; k < NJ; ++k) a += s[k][g];
    ssl[g] = xsum(a);  // full subsum on all lanes
  }

  float v[5];
#pragma unroll
  for (int g = 0; g < 5; ++g) {
    float a = Mt[T[g][0]] * ssl[0];
#pragma unroll
    for (int h = 1; h < 5; ++h) a += Mt[T[g][h]] * ssl[h];
    v[g] = a;
  }

  float sc[NJ];
#pragma unroll
  for (int k = 0; k < NJ; ++k) {
    float a = s[k][0] * v[0];
#pragma unroll
    for (int g = 1; g < 5; ++g) a += s[k][g] * v[g];
    sc[k] = a;
  }
  sc[NJ - 1] = lastv ? sc[NJ - 1] : -3.0e38f;

  float ml = sc[0];
#pragma unroll
  for (int k = 1; k < NJ; ++k) ml = fmaxf(ml, sc[k]);
  float m = xmax(ml);

  float d = 0.f, pl[5] = {0.f, 0.f, 0.f, 0.f, 0.f};
#pragma unroll
  for (int k = 0; k < NJ; ++k) {
    float e = __expf(sc[k] - m);  // masked k: exp(-huge)=0
    d += e;
#pragma unroll
    for (int g = 0; g < 5; ++g) pl[g] += e * s[k][g];
  }
  d = xsum(d);
  float inv = 1.0f / d;
#pragma unroll
  for (int g = 0; g < 5; ++g) pl[g] = xsum(pl[g]);
  if (q == 0) {
#pragma unroll
    for (int g = 0; g < 5; ++g) ob[OUTOFF + g] = pl[g] * inv;
  }
}

// LDS (float4 units): buf0 [0,1560) | buf1 [1560,3120) | outbuf [3120,3400)
// = 54.4 KB -> 2 blocks/CU.
__global__ __launch_bounds__(256, 2) void meso_kernel(
    const float* __restrict__ x, const float* __restrict__ w,
    float* __restrict__ out) {
  __shared__ __align__(16) float4 sm4[3400];
  float* smf = (float*)sm4;
  const int t = threadIdx.x;
  const int wv = t >> 6, ln = t & 63, q = ln & 3, r = ln >> 2;
  const size_t blk = blockIdx.x;
  const float4* xp4 = (const float4*)x + blk * 24960;  // 256*390/4
  float4* o4 = (float4*)out + blk * 2240;              // 256*35/4

  float4 A0, A1, A2, A3, A4, A5, A6 = make_float4(0, 0, 0, 0);
  float4 B0, B1, B2, B3, B4, B5, B6 = make_float4(0, 0, 0, 0);

  // Stage-issue chunk c into reg set (6 full loads + wave3 tail of 24).
#define ISSUE(R, c)                                                    \
  { const float4* g_ = xp4 + (size_t)(c) * 1560;                       \
    R##0 = g_[t];        R##1 = g_[t + 256];  R##2 = g_[t + 512];      \
    R##3 = g_[t + 768];  R##4 = g_[t + 1024]; R##5 = g_[t + 1280];     \
    if (t >= 232) R##6 = g_[1304 + t]; }

#define WRITE(R, b)                                                    \
  { float4* l_ = sm4 + (b) * 1560;                                     \
    l_[t] = R##0;        l_[t + 256] = R##1;  l_[t + 512] = R##2;      \
    l_[t + 768] = R##3;  l_[t + 1024] = R##4; l_[t + 1280] = R##5;     \
    if (t >= 232) l_[1304 + t] = R##6; }

  // n = #VMEM ops this wave issued after the awaited chunk's last load
  // (wave3 carries the 24-lane tail -> 7 loads/chunk vs 6).
#define WAITC(n03, n3)                                                 \
  { if (wv == 3) asm volatile("s_waitcnt vmcnt(" #n3 ")" ::: "memory");\
    else         asm volatile("s_waitcnt vmcnt(" #n03 ")" ::: "memory"); }

#define BAR()                                                          \
  { asm volatile("s_waitcnt lgkmcnt(0)" ::: "memory");                 \
    __builtin_amdgcn_s_barrier();                                      \
    __builtin_amdgcn_sched_barrier(0); }

#define FLUSH(pp)                                                      \
  { if (ln < 35)                                                       \
      o4[(size_t)(pp) * 140 + wv * 35 + ln] =                          \
          sm4[3120 + ((pp) & 1) * 140 + wv * 35 + ln]; }

#define COMPUTE(par)                                                   \
  { const float* bp = smf + (par) * 6240 + r * 390;                    \
    float* ob = smf + 12480 + (par) * 560 + r * 35;                    \
    if (wv == 0) { seg64<25, 115, 15>(bp, q, Mt, ob); }                \
    else if (wv == 1) { seg64<12, 330, 30>(bp, q, Mt, ob);             \
                        seg64<5,  0,   0 >(bp, q, Mt, ob); }           \
    else if (wv == 2) { seg64<9,  25,  5 >(bp, q, Mt, ob);             \
                        seg64<9,  70,  10>(bp, q, Mt, ob); }           \
    else              { seg64<9,  240, 20>(bp, q, Mt, ob);             \
                        seg64<9,  285, 25>(bp, q, Mt, ob); } }

  ISSUE(A, 0)
  ISSUE(B, 1)

  // Mt = upper-tri(W W^T) from uniform scalar loads, overlapping load latency.
  float Mt[15];
  {
    int i = 0;
#pragma unroll
    for (int g = 0; g < 5; ++g)
#pragma unroll
      for (int h = g; h < 5; ++h, ++i) {
        float a = 0.f;
#pragma unroll
        for (int k = 0; k < 10; ++k) a += w[g * 10 + k] * w[h * 10 + k];
        Mt[i] = a;
      }
  }

  WAITC(6, 7)      // chunk0 complete (newer = chunk1's 6/7 loads)
  WRITE(A, 0)
  BAR()

#pragma unroll 1
  for (int p = 0; p < 16; p += 2) {
    // ---- even phase p: compute buf0/out0; B holds chunk p+1 ----
    if (p > 0) FLUSH(p - 1)
    if (p + 2 < 16) ISSUE(A, p + 2)
    COMPUTE(0)
    if (p == 0)       WAITC(6, 7)   // newer = issue(p+2) only
    else if (p < 14)  WAITC(7, 8)   // newer = flush store + issue(p+2)
    else              WAITC(1, 1)   // p=14: newer = flush store only
    WRITE(B, 1)
    BAR()

    // ---- odd phase p+1: compute buf1/out1; A holds chunk p+2 ----
    FLUSH(p)
    if (p + 3 < 16) ISSUE(B, p + 3)
    COMPUTE(1)
    if (p + 2 < 16) {
      if (p + 1 < 14) WAITC(7, 8)
      else            WAITC(1, 1)
      WRITE(A, 0)
    }
    BAR()
  }
  FLUSH(15)
}

extern "C" void kernel_launch(void* const* d_in, const int* in_sizes, int n_in,
                              void* d_out, int out_size, void* d_ws, size_t ws_size,
                              hipStream_t stream) {
  const float* x = (const float*)d_in[0];
  const float* w = (const float*)d_in[1];
  float* out = (float*)d_out;
  int B = in_sizes[0] / 390;  // 131072
  int grid = B / 256;         // 512 blocks = 2/CU, all resident
  meso_kernel<<<grid, 256, 0, stream>>>(x, w, out);
}